// Round 7
// baseline (217.107 us; speedup 1.0000x reference)
//
#include <hip/hip_runtime.h>

// out[s,b,d] = x[s,b,d] + pe[s,d] + (any_p peaks[b,p]==s ? table[s,d] : 0)
// S=256, B=2048, D=256, P=8. Pure stream: 512MB read + 512MB write.
//
// R7: flat grid-stride sweep (the m13-copy / fillBuffer layout): 2048 blocks
// x 256 threads, stride 2^19 f32x4 = 8MB sliding window, 64 steps. Per
// thread b,d4 are stride-invariant and s = s0 + 4k, so:
//   - peak hits over the thread's 64 s-values = one wave-uniform u64 (prologue)
//   - pe[s][d4] evolves by a fixed-angle rotation (8 FMA/iter, no loads)
//   - table[s] row loaded only on hit (~3% of iters, wave-uniform branch)
// Loads/stores nontemporal (R2-R6 established NT/NT as best).

typedef float f32x4 __attribute__((ext_vector_type(4)));

namespace {
constexpr int S       = 256;
constexpr int Bn      = 2048;
constexpr int P       = 8;
constexpr int D4      = 64;                   // 256 floats / 4
constexpr int THREADS = 256;
constexpr int BLOCKS  = 2048;                 // exactly one resident round
constexpr int GSTRIDE = BLOCKS * THREADS;     // 524288 f32x4 = 8 MB per step
constexpr int KITER   = (S * Bn * D4) / GSTRIDE;  // 64
}

__global__ __launch_bounds__(THREADS)
void pe_peak_flat(const float* __restrict__ x,
                  const unsigned* __restrict__ pk,   // int32 or int64 data
                  const float* __restrict__ table,
                  float* __restrict__ out)
{
    const int t  = threadIdx.x;
    const int g  = blockIdx.x * THREADS + t;
    const int d4 = g & 63;                 // f32x4 column, invariant
    const int b  = (g >> 6) & (Bn - 1);    // batch, invariant, wave-uniform
    const int s0 = g >> 17;                // 0..3, wave-uniform

    // --- int64 vs int32 width detect (per wave, all waves): values < 300 =>
    //     int64 high words all zero; 64 consecutive zero odd-words for int32
    //     data is ~impossible. ------------------------------------------------
    const unsigned hw = pk[2 * (t & 63) + 1];
    const bool is64 = (__ballot(hw != 0u) == 0ull);

    // --- per-thread hit bitmask: bit k <=> some peak of batch b equals s0+4k
    unsigned long long hm = 0;
    if (is64) {
        #pragma unroll
        for (int p = 0; p < P; ++p) {
            unsigned v = pk[(size_t)(b * P + p) * 2];
            if (v < (unsigned)S && (v & 3u) == (unsigned)s0) hm |= 1ull << (v >> 2);
        }
    } else {
        #pragma unroll
        for (int p = 0; p < P; ++p) {
            unsigned v = pk[b * P + p];
            if (v < (unsigned)S && (v & 3u) == (unsigned)s0) hm |= 1ull << (v >> 2);
        }
    }
    // nudge the hit mask into SGPRs (it is wave-uniform by construction)
    const unsigned hmlo = __builtin_amdgcn_readfirstlane((unsigned)hm);
    const unsigned hmhi = __builtin_amdgcn_readfirstlane((unsigned)(hm >> 32));
    const unsigned long long hmu = ((unsigned long long)hmhi << 32) | hmlo;

    // --- pe init at s=s0 and per-step rotation constants (step = 4 in s) ----
    const float c  = -6.907755278982137f / 256.0f;       // -ln(1000)/D
    const float f0 = expf((float)(4 * d4) * c);          // pair 2*d4
    const float f1 = expf((float)(4 * d4 + 2) * c);      // pair 2*d4+1
    float sa = sinf((float)s0 * f0), ca = cosf((float)s0 * f0);
    float sb = sinf((float)s0 * f1), cb = cosf((float)s0 * f1);
    const float r0c = cosf(4.0f * f0), r0s = sinf(4.0f * f0);
    const float r1c = cosf(4.0f * f1), r1s = sinf(4.0f * f1);

    // --- flat sliding-window stream -----------------------------------------
    const f32x4* __restrict__ xr = reinterpret_cast<const f32x4*>(x);
    f32x4* __restrict__ ow       = reinterpret_cast<f32x4*>(out);
    const f32x4* __restrict__ tr = reinterpret_cast<const f32x4*>(table);

    size_t off  = (size_t)g;            // f32x4 units
    int    tidx = s0 * D4 + d4;         // table row element, +4*D4 per step

    #pragma unroll 8
    for (int k = 0; k < KITER; ++k) {
        f32x4 v = __builtin_nontemporal_load(xr + off);
        f32x4 r;
        r.x = v.x + sa; r.y = v.y + ca;
        r.z = v.z + sb; r.w = v.w + cb;
        if ((hmu >> k) & 1ull) {        // wave-uniform, ~3% taken
            f32x4 tb = tr[tidx];
            r += tb;
        }
        __builtin_nontemporal_store(r, ow + off);
        // rotate pe by delta-angle 4*f (advance s by 4)
        float nsa = sa * r0c + ca * r0s, nca = ca * r0c - sa * r0s;
        float nsb = sb * r1c + cb * r1s, ncb = cb * r1c - sb * r1s;
        sa = nsa; ca = nca; sb = nsb; cb = ncb;
        off  += (size_t)GSTRIDE;
        tidx += 4 * D4;
    }
}

extern "C" void kernel_launch(void* const* d_in, const int* in_sizes, int n_in,
                              void* d_out, int out_size, void* d_ws, size_t ws_size,
                              hipStream_t stream) {
    const float*    x     = (const float*)d_in[0];
    const unsigned* pk    = (const unsigned*)d_in[1];
    const float*    table = (const float*)d_in[2];
    float*          out   = (float*)d_out;

    pe_peak_flat<<<dim3(BLOCKS), dim3(THREADS), 0, stream>>>(x, pk, table, out);
}

// Round 8
// 200.700 us; speedup vs baseline: 1.0818x; 1.0818x over previous
//
#include <hip/hip_runtime.h>

// out[s,b,d] = x[s,b,d] + pe[s,d] + (any_p peaks[b,p]==s ? table[s,d] : 0)
// S=256, B=2048, D=256, P=8. Pure stream: 512MB read + 512MB write.
//
// FINAL (= R2, session best: 201 us, 5.34 TB/s). In-situ roofline evidence:
// a copy-shaped kernel (R7 flat sweep, strictly less work) ran 217 us; the
// full 2x2 NT/plain policy matrix, barrier-free split (R4), and occupancy
// variants (R3) all regressed. NT load + NT store, LDS-free hot loop:
// pe / pe+table hoisted to registers (d-index loop-invariant per thread),
// peak-hit mask balloted into two u64 registers.

typedef float f32x4 __attribute__((ext_vector_type(4)));

namespace {
constexpr int S       = 256;
constexpr int Bn      = 2048;
constexpr int P       = 8;
constexpr int D4      = 64;            // 256 floats / 4
constexpr int BTILE   = 128;           // batches per block
constexpr int NBT     = Bn / BTILE;    // 16
constexpr int THREADS = 256;
constexpr int ITERS   = BTILE * D4 / THREADS;  // 32 float4 per thread
}

__global__ __launch_bounds__(THREADS)
void pe_peak_kernel(const float* __restrict__ x,
                    const unsigned* __restrict__ pk,   // int32 or int64 data
                    const float* __restrict__ table,
                    float* __restrict__ out)
{
    __shared__ f32x4 s_pe[D4];           // pe[s, :]
    __shared__ f32x4 s_pt[D4];           // pe[s, :] + table[s, :]
    __shared__ unsigned long long s_mb[2];  // 128 per-batch peak-hit bits
    __shared__ int s_is64;

    const int t  = threadIdx.x;
    const int s  = blockIdx.x >> 4;               // / NBT
    const int b0 = (blockIdx.x & (NBT - 1)) * BTILE;

    // --- int64 vs int32 width detect: values < 300, so int64 => all high
    //     words zero; int32 => 32 consecutive zero words ~impossible. --------
    {
        unsigned hw = (t < 32) ? pk[2 * t + 1] : 0u;
        unsigned long long nz = __ballot(hw != 0u);
        if (t == 0) s_is64 = (nz == 0ull) ? 1 : 0;
    }

    // --- pe[s,:] on the fly + pe+table staged once (threads 0..63) ---------
    if (t < D4) {
        const float c = -6.907755278982137f / 256.0f;   // -ln(1000)/D
        float a0 = (float)s * expf((float)(4 * t) * c);       // pair k=2t
        float a1 = (float)s * expf((float)(4 * t + 2) * c);   // pair k=2t+1
        f32x4 pe4;
        pe4.x = sinf(a0); pe4.y = cosf(a0);
        pe4.z = sinf(a1); pe4.w = cosf(a1);
        f32x4 tb4 = reinterpret_cast<const f32x4*>(table)[s * D4 + t];
        s_pe[t] = pe4;
        s_pt[t] = pe4 + tb4;
    }
    __syncthreads();

    // --- per-batch "peak at s" bit, balloted into 2x u64 -------------------
    bool m = false;
    if (t < BTILE) {
        const int b = b0 + t;
        if (s_is64) {
            #pragma unroll
            for (int p = 0; p < P; ++p) m |= (pk[(size_t)(b * P + p) * 2] == (unsigned)s);
        } else {
            #pragma unroll
            for (int p = 0; p < P; ++p) m |= (pk[b * P + p] == (unsigned)s);
        }
    }
    {
        unsigned long long bal = __ballot(m);
        if (t < 128 && (t & 63) == 0) s_mb[t >> 6] = bal;
    }
    __syncthreads();

    // --- hoist everything the hot loop needs into registers ----------------
    const int lane = t & 63;     // d4 index (loop-invariant)
    const int w    = t >> 6;     // batch-row offset within each 4-row slab
    const f32x4 pe4 = s_pe[lane];
    const f32x4 pt4 = s_pt[lane];
    const unsigned long long mb0 = s_mb[0];
    const unsigned long long mb1 = s_mb[1];

    // --- stream 128x256 floats, batched 8 loads -> 8 add+stores ------------
    const size_t base = ((size_t)s * Bn + b0) * D4;
    const f32x4* __restrict__ xr = reinterpret_cast<const f32x4*>(x) + base;
    f32x4* __restrict__ orow     = reinterpret_cast<f32x4*>(out) + base;

    #pragma unroll
    for (int j0 = 0; j0 < ITERS; j0 += 8) {
        f32x4 v[8];
        #pragma unroll
        for (int u = 0; u < 8; ++u)
            v[u] = __builtin_nontemporal_load(xr + (size_t)(j0 + u) * THREADS + t);
        #pragma unroll
        for (int u = 0; u < 8; ++u) {
            const int j = j0 + u;
            const unsigned long long mb = (j < 16) ? mb0 : mb1;   // compile-time select
            const bool hit = (mb >> ((4 * j + w) & 63)) & 1ull;
            const f32x4 a = hit ? pt4 : pe4;
            __builtin_nontemporal_store(v[u] + a, orow + (size_t)j * THREADS + t);
        }
    }
}

extern "C" void kernel_launch(void* const* d_in, const int* in_sizes, int n_in,
                              void* d_out, int out_size, void* d_ws, size_t ws_size,
                              hipStream_t stream) {
    const float*    x     = (const float*)d_in[0];
    const unsigned* pk    = (const unsigned*)d_in[1];
    const float*    table = (const float*)d_in[2];
    float*          out   = (float*)d_out;

    pe_peak_kernel<<<dim3(S * NBT), dim3(THREADS), 0, stream>>>(x, pk, table, out);
}